// Round 2
// baseline (839.493 us; speedup 1.0000x reference)
//
#include <hip/hip_runtime.h>

// VQ-VAE vector quantizer, MI355X — bitwise emulation of the numpy f32 reference.
// z: (4,256,16,32,32) f32 ; emb: (1024,256) f32
// out (f32, concatenated): z_q_st[16777216] | vq_loss | perplexity | indices[65536]
//
// Reference math (f32 throughout):
//   x_sq[n] = np pairwise sum of fl32(z*z) over 256   (two 128-blocks, 8 accumulators)
//   e_sq[k] = same over emb rows
//   xe[n][k] = sgemm f32: sequential FMA chain over c=0..255
//   d = fl32( fl32(x_sq + e_sq) - 2*xe ), argmin first-min tie-break.

#define C_DIM 256
#define K_CODES 1024
#define N_VEC 65536
#define BN 64
#define BK 64
#define PADF 260   // f32 LDS row pitch: 1040 B, 16B-aligned; et reads 2-way (free)

#define OUT_ZQ_SIZE 16777216
#define OUT_LOSS_OFF 16777216
#define OUT_PP_OFF   16777217
#define OUT_IDX_OFF  16777218

// ws: [0,4096) e_sq f32[1024] ; [4096,266240) x_sq f32[65536] ;
//     [266240,270336) counts u32[1024] ; [270336,270344) loss f64

// numpy pairwise_sum of squares for a contiguous 128-block (PW_BLOCKSIZE path)
__device__ __forceinline__ float pairwise_sq_128(const float* p) {
#pragma clang fp contract(off)
    float r[8];
#pragma unroll
    for (int j = 0; j < 8; ++j) { float v = p[j]; r[j] = v * v; }
#pragma unroll
    for (int i = 8; i < 128; i += 8)
#pragma unroll
        for (int j = 0; j < 8; ++j) { float v = p[i + j]; float t = v * v; r[j] = r[j] + t; }
    return ((r[0] + r[1]) + (r[2] + r[3])) + ((r[4] + r[5]) + (r[6] + r[7]));
}

__global__ __launch_bounds__(256) void esq_kernel(const float* __restrict__ emb,
                                                  float* __restrict__ esq) {
#pragma clang fp contract(off)
    __shared__ float tile[64 * PADF];
    const int tid = threadIdx.x;
    const int k0 = blockIdx.x * 64;
#pragma unroll
    for (int r = 0; r < 64; ++r) {
        int idx = r * 256 + tid;
        tile[(idx >> 8) * PADF + (idx & 255)] = emb[k0 * C_DIM + idx];
    }
    __syncthreads();
    if (tid < 64) {
        const float* row = &tile[tid * PADF];
        float res = pairwise_sq_128(row) + pairwise_sq_128(row + 128);
        esq[k0 + tid] = res;
    }
}

__global__ __launch_bounds__(256) void xsq_kernel(const float* __restrict__ z,
                                                  float* __restrict__ xsq) {
#pragma clang fp contract(off)
    const int n = blockIdx.x * 256 + threadIdx.x;
    const int b = n >> 14, s = n & 16383;
    const float* base = z + ((size_t)b << 22) + s;
    float r[8], res;
    // first 128-block
#pragma unroll
    for (int j = 0; j < 8; ++j) { float v = base[(size_t)j << 14]; r[j] = v * v; }
#pragma unroll
    for (int i = 8; i < 128; i += 8)
#pragma unroll
        for (int j = 0; j < 8; ++j) { float v = base[(size_t)(i + j) << 14]; float t = v * v; r[j] = r[j] + t; }
    res = ((r[0] + r[1]) + (r[2] + r[3])) + ((r[4] + r[5]) + (r[6] + r[7]));
    // second 128-block
#pragma unroll
    for (int j = 0; j < 8; ++j) { float v = base[(size_t)(128 + j) << 14]; r[j] = v * v; }
#pragma unroll
    for (int i = 136; i < 256; i += 8)
#pragma unroll
        for (int j = 0; j < 8; ++j) { float v = base[(size_t)(i + j) << 14]; float t = v * v; r[j] = r[j] + t; }
    res = res + (((r[0] + r[1]) + (r[2] + r[3])) + ((r[4] + r[5]) + (r[6] + r[7])));
    xsq[n] = res;
}

__global__ __launch_bounds__(256) void argmin_kernel(
    const float* __restrict__ z, const float* __restrict__ emb,
    const float* __restrict__ esq, const float* __restrict__ xsq,
    float* __restrict__ out_idx, unsigned* __restrict__ counts) {
#pragma clang fp contract(off)
    __shared__ float zt[BN * PADF];
    __shared__ float et[BK * PADF];
    __shared__ float esql[BK];
    __shared__ float xsl[BN];

    const int tid = threadIdx.x;
    const int tn = tid >> 4;      // 0..15
    const int tk = tid & 15;      // 0..15
    const int n0 = blockIdx.x * BN;
    const int b  = n0 >> 14;
    const int s0 = n0 & 16383;
    const float* zb = z + ((size_t)b << 22) + s0;

    // stage z tile: zt[nl][c] (coalesced: 64 consecutive n per c)
#pragma unroll
    for (int r = 0; r < 64; ++r) {
        int idx = r * 256 + tid;
        int nl = idx & 63;
        int c  = idx >> 6;
        zt[nl * PADF + c] = zb[((size_t)c << 14) + nl];
    }
    if (tid < BN) xsl[tid] = xsq[n0 + tid];

    float minv[4];
    int   mini[4];
#pragma unroll
    for (int i = 0; i < 4; ++i) { minv[i] = 3.4e38f; mini[i] = 0; }

    for (int k0 = 0; k0 < K_CODES; k0 += BK) {
        __syncthreads();   // protect et reuse across tiles
        const float* eb = emb + (size_t)k0 * C_DIM;
#pragma unroll
        for (int r = 0; r < 64; ++r) {
            int idx = r * 256 + tid;
            et[(idx >> 8) * PADF + (idx & 255)] = eb[idx];
        }
        if (tid < BK) esql[tid] = esq[k0 + tid];
        __syncthreads();

        float dot[4][4];
#pragma unroll
        for (int i = 0; i < 4; ++i)
#pragma unroll
            for (int j = 0; j < 4; ++j) dot[i][j] = 0.0f;

        // sequential FMA chain over c (ascending) — matches BLAS sgemm accumulation
        for (int c = 0; c < C_DIM; c += 4) {
            float4 zv[4], ev[4];
#pragma unroll
            for (int i = 0; i < 4; ++i)
                zv[i] = *reinterpret_cast<const float4*>(&zt[(tn + 16 * i) * PADF + c]);
#pragma unroll
            for (int j = 0; j < 4; ++j)
                ev[j] = *reinterpret_cast<const float4*>(&et[(tk + 16 * j) * PADF + c]);
#pragma unroll
            for (int i = 0; i < 4; ++i)
#pragma unroll
                for (int j = 0; j < 4; ++j) {
                    float a = dot[i][j];
                    a = fmaf(zv[i].x, ev[j].x, a);
                    a = fmaf(zv[i].y, ev[j].y, a);
                    a = fmaf(zv[i].z, ev[j].z, a);
                    a = fmaf(zv[i].w, ev[j].w, a);
                    dot[i][j] = a;
                }
        }

#pragma unroll
        for (int i = 0; i < 4; ++i)
#pragma unroll
            for (int j = 0; j < 4; ++j) {
                int kg = k0 + tk + 16 * j;
                float t1 = xsl[tn + 16 * i] + esql[tk + 16 * j];  // fl32(x_sq + e_sq)
                float m2 = 2.0f * dot[i][j];                       // exact
                float r  = t1 - m2;                                // fl32(t1 - 2xe)
                if (r < minv[i] || (r == minv[i] && kg < mini[i])) { minv[i] = r; mini[i] = kg; }
            }
    }

    // reduce across the 16 tk lanes sharing each tn
#pragma unroll
    for (int i = 0; i < 4; ++i) {
        for (int off = 8; off >= 1; off >>= 1) {
            float ov = __shfl_xor(minv[i], off, 64);
            int   oi = __shfl_xor(mini[i], off, 64);
            if (ov < minv[i] || (ov == minv[i] && oi < mini[i])) { minv[i] = ov; mini[i] = oi; }
        }
        if (tk == 0) {
            int n = n0 + tn + 16 * i;
            out_idx[n] = (float)mini[i];
            atomicAdd(&counts[mini[i]], 1u);
        }
    }
}

__global__ __launch_bounds__(256) void gather_kernel(
    const float* __restrict__ z, const float* __restrict__ emb,
    const float* __restrict__ out_idx, float* __restrict__ out,
    double* __restrict__ loss_acc) {
    int t = blockIdx.x * 256 + threadIdx.x;
    double local = 0.0;
#pragma unroll
    for (int it = 0; it < 8; ++it) {
        int f = t + it * 2097152;
        int b = f >> 22;
        int s = f & 16383;
        int c = (f >> 14) & 255;
        int n = (b << 14) | s;
        int idx = (int)out_idx[n];
        float zv = z[f];
        float d = emb[idx * C_DIM + c] - zv;   // z_q - z (f32, matches ref elementwise)
        out[f] = zv + d;                        // z + (z_q - z)
        local += (double)d * (double)d;
    }
    for (int off = 32; off >= 1; off >>= 1) local += __shfl_down(local, off, 64);
    __shared__ double red[4];
    if ((threadIdx.x & 63) == 0) red[threadIdx.x >> 6] = local;
    __syncthreads();
    if (threadIdx.x == 0) {
        double s = red[0] + red[1] + red[2] + red[3];
        atomicAdd(loss_acc, s);
    }
}

__global__ void finalize_kernel(const unsigned* __restrict__ counts,
                                const double* __restrict__ loss_acc,
                                float* __restrict__ out) {
    int tid = threadIdx.x;
    double s = 0.0;
    for (int k = tid; k < K_CODES; k += 256) {
        float avg = (float)counts[k] / 65536.0f;
        float t = avg * logf(avg + 1e-10f);
        s += (double)t;
    }
    for (int off = 32; off >= 1; off >>= 1) s += __shfl_down(s, off, 64);
    __shared__ double red[4];
    if ((tid & 63) == 0) red[tid >> 6] = s;
    __syncthreads();
    if (tid == 0) {
        double tot = red[0] + red[1] + red[2] + red[3];
        out[OUT_PP_OFF]   = expf((float)(-tot));
        out[OUT_LOSS_OFF] = 1.25f * (float)(loss_acc[0] / 16777216.0);
    }
}

extern "C" void kernel_launch(void* const* d_in, const int* in_sizes, int n_in,
                              void* d_out, int out_size, void* d_ws, size_t ws_size,
                              hipStream_t stream) {
    const float* z   = (const float*)d_in[0];
    const float* emb = (const float*)d_in[1];
    float* out = (float*)d_out;

    float*    esq      = (float*)d_ws;
    float*    xsq      = (float*)((char*)d_ws + 4096);
    unsigned* counts   = (unsigned*)((char*)d_ws + 266240);
    double*   loss_acc = (double*)((char*)d_ws + 270336);
    float*    out_idx  = out + OUT_IDX_OFF;

    hipMemsetAsync((char*)d_ws + 266240, 0, 4104, stream);   // counts + loss accum
    esq_kernel<<<K_CODES / 64, 256, 0, stream>>>(emb, esq);
    xsq_kernel<<<N_VEC / 256, 256, 0, stream>>>(z, xsq);
    argmin_kernel<<<N_VEC / BN, 256, 0, stream>>>(z, emb, esq, xsq, out_idx, counts);
    gather_kernel<<<OUT_ZQ_SIZE / (256 * 8), 256, 0, stream>>>(z, emb, out_idx, out, loss_acc);
    finalize_kernel<<<1, 256, 0, stream>>>(counts, loss_acc, out);
}

// Round 3
// 610.344 us; speedup vs baseline: 1.3754x; 1.3754x over previous
//
#include <hip/hip_runtime.h>

// VQ-VAE vector quantizer, MI355X — bitwise emulation of the numpy f32 reference.
// z: (4,256,16,32,32) f32 ; emb: (1024,256) f32
// out (f32, concatenated): z_q_st[16777216] | vq_loss | perplexity | indices[65536]
//
// Exactness contract (validated round 2, absmax 0):
//   x_sq[n], e_sq[k]: numpy pairwise sum of fl32(v*v) (two 128-blocks, 8 accumulators)
//   xe[n][k]: single sequential f32 FMA chain over c = 0..255 (BLAS sgemm order)
//   d = fl32( fl32(x_sq + e_sq) - 2*xe ), argmin with first-min tie-break.
//
// Round-3 structure: argmin was LDS-BW-bound (2 B LDS/FMA, 1 wave/SIMD).
//   - 8n x 8k register tile (1 B LDS/FMA on z only)
//   - e read from pre-transposed embT[c][k] via global (L1/L2), off the LDS pipe
//   - z staged [c][n] in 32 KB chunks -> 2 blocks/CU

#define C_DIM 256
#define K_CODES 1024
#define N_VEC 65536
#define BN 128
#define BK 128
#define CB 64

#define OUT_ZQ_SIZE 16777216
#define OUT_LOSS_OFF 16777216
#define OUT_PP_OFF   16777217
#define OUT_IDX_OFF  16777218

// ws: [0,1048576) embT f32[256][1024] ; [1048576,1052672) esq f32[1024] ;
//     [1052672,1314816) xsq f32[65536] ; [1314816,1318912) counts u32[1024] ;
//     [1318912,1318920) loss f64

__global__ __launch_bounds__(256) void transpose_kernel(const float* __restrict__ emb,
                                                        float* __restrict__ embT) {
    __shared__ float t[64][65];
    const int k0 = blockIdx.x * 64;
    const int c0 = blockIdx.y * 64;
    const int tx = threadIdx.x & 63, ty = threadIdx.x >> 6;
    for (int r = ty; r < 64; r += 4)
        t[r][tx] = emb[(k0 + r) * C_DIM + c0 + tx];
    __syncthreads();
    for (int r = ty; r < 64; r += 4)
        embT[(c0 + r) * K_CODES + k0 + tx] = t[tx][r];
}

// numpy pairwise_sum of squares for a contiguous 128-block
__device__ __forceinline__ float pairwise_sq_128(const float* p) {
#pragma clang fp contract(off)
    float r[8];
#pragma unroll
    for (int j = 0; j < 8; ++j) { float v = p[j]; r[j] = v * v; }
#pragma unroll
    for (int i = 8; i < 128; i += 8)
#pragma unroll
        for (int j = 0; j < 8; ++j) { float v = p[i + j]; float t = v * v; r[j] = r[j] + t; }
    return ((r[0] + r[1]) + (r[2] + r[3])) + ((r[4] + r[5]) + (r[6] + r[7]));
}

__global__ __launch_bounds__(256) void esq_kernel(const float* __restrict__ emb,
                                                  float* __restrict__ esq) {
#pragma clang fp contract(off)
    __shared__ float tile[64 * 260];
    const int tid = threadIdx.x;
    const int k0 = blockIdx.x * 64;
#pragma unroll
    for (int r = 0; r < 64; ++r) {
        int idx = r * 256 + tid;
        tile[(idx >> 8) * 260 + (idx & 255)] = emb[k0 * C_DIM + idx];
    }
    __syncthreads();
    if (tid < 64) {
        const float* row = &tile[tid * 260];
        esq[k0 + tid] = pairwise_sq_128(row) + pairwise_sq_128(row + 128);
    }
}

__global__ __launch_bounds__(256) void xsq_kernel(const float* __restrict__ z,
                                                  float* __restrict__ xsq) {
#pragma clang fp contract(off)
    const int n = blockIdx.x * 256 + threadIdx.x;
    const int b = n >> 14, s = n & 16383;
    const float* base = z + ((size_t)b << 22) + s;
    float r[8], res;
#pragma unroll
    for (int j = 0; j < 8; ++j) { float v = base[(size_t)j << 14]; r[j] = v * v; }
#pragma unroll
    for (int i = 8; i < 128; i += 8)
#pragma unroll
        for (int j = 0; j < 8; ++j) { float v = base[(size_t)(i + j) << 14]; float t = v * v; r[j] = r[j] + t; }
    res = ((r[0] + r[1]) + (r[2] + r[3])) + ((r[4] + r[5]) + (r[6] + r[7]));
#pragma unroll
    for (int j = 0; j < 8; ++j) { float v = base[(size_t)(128 + j) << 14]; r[j] = v * v; }
#pragma unroll
    for (int i = 136; i < 256; i += 8)
#pragma unroll
        for (int j = 0; j < 8; ++j) { float v = base[(size_t)(i + j) << 14]; float t = v * v; r[j] = r[j] + t; }
    res = res + (((r[0] + r[1]) + (r[2] + r[3])) + ((r[4] + r[5]) + (r[6] + r[7])));
    xsq[n] = res;
}

__global__ __launch_bounds__(256, 2) void argmin_kernel(
    const float* __restrict__ z, const float* __restrict__ embT,
    const float* __restrict__ esq, const float* __restrict__ xsq,
    float* __restrict__ out_idx, unsigned* __restrict__ counts) {
#pragma clang fp contract(off)
    __shared__ float zs[CB * BN];   // [c][n], 32 KB

    const int tid = threadIdx.x;
    const int tn = tid >> 4;        // 0..15 -> n-octet
    const int tk = tid & 15;        // 0..15 -> k-octet
    const int n0 = blockIdx.x * BN;
    const int b  = n0 >> 14;
    const int s0 = n0 & 16383;
    const float* zb = z + ((size_t)b << 22) + s0;

    float xsl[8];
    {
        float4 a = *reinterpret_cast<const float4*>(&xsq[n0 + 8 * tn]);
        float4 c = *reinterpret_cast<const float4*>(&xsq[n0 + 8 * tn + 4]);
        xsl[0] = a.x; xsl[1] = a.y; xsl[2] = a.z; xsl[3] = a.w;
        xsl[4] = c.x; xsl[5] = c.y; xsl[6] = c.z; xsl[7] = c.w;
    }

    float minv[8];
    int   mini[8];
#pragma unroll
    for (int i = 0; i < 8; ++i) { minv[i] = 3.4e38f; mini[i] = 0; }

    for (int kt = 0; kt < K_CODES / BK; ++kt) {
        const int k0 = kt * BK;
        float esql[8];
        {
            float4 a = *reinterpret_cast<const float4*>(&esq[k0 + 8 * tk]);
            float4 c = *reinterpret_cast<const float4*>(&esq[k0 + 8 * tk + 4]);
            esql[0] = a.x; esql[1] = a.y; esql[2] = a.z; esql[3] = a.w;
            esql[4] = c.x; esql[5] = c.y; esql[6] = c.z; esql[7] = c.w;
        }

        float acc[8][8];
#pragma unroll
        for (int i = 0; i < 8; ++i)
#pragma unroll
            for (int j = 0; j < 8; ++j) acc[i][j] = 0.0f;

        for (int cc = 0; cc < C_DIM / CB; ++cc) {
            const int c0 = cc * CB;
            __syncthreads();   // previous chunk fully consumed
            // stage zs[c][n] chunk: 2048 float4, 8 per thread, coalesced
#pragma unroll
            for (int r = 0; r < 8; ++r) {
                int lin  = r * 256 + tid;       // float4 id
                int cl   = lin >> 5;            // 0..63
                int u    = lin & 31;            // float4 within row of 128
                float4 v = *reinterpret_cast<const float4*>(
                    zb + ((size_t)(c0 + cl) << 14) + u * 4);
                *reinterpret_cast<float4*>(&zs[cl * BN + u * 4]) = v;
            }
            __syncthreads();

            const float* ecol = embT + (size_t)c0 * K_CODES + k0 + 8 * tk;
#pragma unroll 2
            for (int c = 0; c < CB; ++c) {
                float4 z0 = *reinterpret_cast<const float4*>(&zs[c * BN + 8 * tn]);
                float4 z1 = *reinterpret_cast<const float4*>(&zs[c * BN + 8 * tn + 4]);
                const float* ep = ecol + (size_t)c * K_CODES;
                float4 e0 = *reinterpret_cast<const float4*>(ep);
                float4 e1 = *reinterpret_cast<const float4*>(ep + 4);
                float zr[8] = {z0.x, z0.y, z0.z, z0.w, z1.x, z1.y, z1.z, z1.w};
                float er[8] = {e0.x, e0.y, e0.z, e0.w, e1.x, e1.y, e1.z, e1.w};
#pragma unroll
                for (int i = 0; i < 8; ++i)
#pragma unroll
                    for (int j = 0; j < 8; ++j)
                        acc[i][j] = fmaf(zr[i], er[j], acc[i][j]);
            }
        }

        // distances + running first-min (kg strictly ascending per thread)
#pragma unroll
        for (int j = 0; j < 8; ++j) {
            int kg = k0 + 8 * tk + j;
#pragma unroll
            for (int i = 0; i < 8; ++i) {
                float t1 = xsl[i] + esql[j];
                float r  = t1 - 2.0f * acc[i][j];
                if (r < minv[i]) { minv[i] = r; mini[i] = kg; }
            }
        }
    }

    // reduce across the 16 tk lanes sharing each tn (16 consecutive lanes)
#pragma unroll
    for (int i = 0; i < 8; ++i) {
        for (int off = 8; off >= 1; off >>= 1) {
            float ov = __shfl_xor(minv[i], off, 64);
            int   oi = __shfl_xor(mini[i], off, 64);
            if (ov < minv[i] || (ov == minv[i] && oi < mini[i])) { minv[i] = ov; mini[i] = oi; }
        }
    }
    if (tk == 0) {
#pragma unroll
        for (int i = 0; i < 8; ++i) {
            int n = n0 + 8 * tn + i;
            out_idx[n] = (float)mini[i];
            atomicAdd(&counts[mini[i]], 1u);
        }
    }
}

__global__ __launch_bounds__(256) void gather_kernel(
    const float* __restrict__ z, const float* __restrict__ emb,
    const float* __restrict__ out_idx, float* __restrict__ out,
    double* __restrict__ loss_acc) {
    int t = blockIdx.x * 256 + threadIdx.x;
    double local = 0.0;
#pragma unroll
    for (int it = 0; it < 8; ++it) {
        int f = t + it * 2097152;
        int b = f >> 22;
        int s = f & 16383;
        int c = (f >> 14) & 255;
        int n = (b << 14) | s;
        int idx = (int)out_idx[n];
        float zv = z[f];
        float d = emb[idx * C_DIM + c] - zv;   // z_q - z
        out[f] = zv + d;                        // z + (z_q - z)
        local += (double)d * (double)d;
    }
    for (int off = 32; off >= 1; off >>= 1) local += __shfl_down(local, off, 64);
    __shared__ double red[4];
    if ((threadIdx.x & 63) == 0) red[threadIdx.x >> 6] = local;
    __syncthreads();
    if (threadIdx.x == 0) {
        double s = red[0] + red[1] + red[2] + red[3];
        atomicAdd(loss_acc, s);
    }
}

__global__ void finalize_kernel(const unsigned* __restrict__ counts,
                                const double* __restrict__ loss_acc,
                                float* __restrict__ out) {
    int tid = threadIdx.x;
    double s = 0.0;
    for (int k = tid; k < K_CODES; k += 256) {
        float avg = (float)counts[k] / 65536.0f;
        float t = avg * logf(avg + 1e-10f);
        s += (double)t;
    }
    for (int off = 32; off >= 1; off >>= 1) s += __shfl_down(s, off, 64);
    __shared__ double red[4];
    if ((tid & 63) == 0) red[tid >> 6] = s;
    __syncthreads();
    if (tid == 0) {
        double tot = red[0] + red[1] + red[2] + red[3];
        out[OUT_PP_OFF]   = expf((float)(-tot));
        out[OUT_LOSS_OFF] = 1.25f * (float)(loss_acc[0] / 16777216.0);
    }
}

extern "C" void kernel_launch(void* const* d_in, const int* in_sizes, int n_in,
                              void* d_out, int out_size, void* d_ws, size_t ws_size,
                              hipStream_t stream) {
    const float* z   = (const float*)d_in[0];
    const float* emb = (const float*)d_in[1];
    float* out = (float*)d_out;

    float*    embT     = (float*)d_ws;
    float*    esq      = (float*)((char*)d_ws + 1048576);
    float*    xsq      = (float*)((char*)d_ws + 1052672);
    unsigned* counts   = (unsigned*)((char*)d_ws + 1314816);
    double*   loss_acc = (double*)((char*)d_ws + 1318912);
    float*    out_idx  = out + OUT_IDX_OFF;

    hipMemsetAsync((char*)d_ws + 1314816, 0, 4104, stream);   // counts + loss
    transpose_kernel<<<dim3(16, 4), 256, 0, stream>>>(emb, embT);
    esq_kernel<<<K_CODES / 64, 256, 0, stream>>>(emb, esq);
    xsq_kernel<<<N_VEC / 256, 256, 0, stream>>>(z, xsq);
    argmin_kernel<<<N_VEC / BN, 256, 0, stream>>>(z, embT, esq, xsq, out_idx, counts);
    gather_kernel<<<OUT_ZQ_SIZE / (256 * 8), 256, 0, stream>>>(z, emb, out_idx, out, loss_acc);
    finalize_kernel<<<1, 256, 0, stream>>>(counts, loss_acc, out);
}